// Round 10
// baseline (18.100 us; speedup 1.0000x reference)
//
#include <hip/hip_runtime.h>
#include <hip/hip_bf16.h>
#include <math.h>

// Problem constants (fixed by the reference setup_inputs)
#define NROWS 2048
#define KROWS 256
#define DDIM  512

typedef __attribute__((ext_vector_type(8))) short short8;
typedef __attribute__((ext_vector_type(4))) short short4v;
typedef __attribute__((ext_vector_type(4))) float f32x4;

__device__ inline short f2bfs(float f) {
    // fp32 -> bf16 RNE (bit manip; compiler-friendly)
    unsigned u = __float_as_uint(f);
    u += 0x7fffu + ((u >> 16) & 1u);
    return (short)(u >> 16);
}

// SINGLE-DISPATCH fused kernel.
// Grid: 256 blocks x 512 threads (8 waves) = 1 block/CU, all resident.
// Block covers 2 mt x 4 ct; wave w -> (mt_local = w>>2, ct = ctbase + (w&3)).
// No workspace, no second kernel, no grid sync:
//   1) cooperative X staging: 32 rows fp32 -> bf16 fragment LDS (32KB) + y2
//   2) all waves read X fragments to registers; barrier frees the region
//   3) 4 phases: stage ct_ph's RAW P/A fp32 (coalesced) -> bf16 fragment LDS
//      (32KB, reusing the X region), compute per-row norms/tanh scalars in
//      the same pass (scale/conf factored OUT of the fragments - they are
//      per-row scalars and are applied in the epilogue instead);
//      waves with (w&3)==ph copy their fragments to registers
//   4) 32-MFMA burst on 4 independent chains; fused analytic epilogue with
//      xp = scale*accP, xa = conf*accA.
// C/D: col = lane&15 (class), row = (lane>>4)*4 + reg (m)   [m89 verified]
__global__ __launch_bounds__(512, 2) void hmlr_one(
        const float* __restrict__ x,
        const float* __restrict__ a_vals,
        const float* __restrict__ p_vals,
        float* __restrict__ out) {
    // Union region: X fragments [2][16][64] chunks (32KB)  OR  P/A fragments
    // [16][64] + [16][64] (16KB + 16KB). Y2S/SCL live outside the union.
    __shared__ __align__(16) char BUF[32768];
    __shared__ float Y2S[32];
    __shared__ float SCL[4][16][6];   // {p2, pa, na, kc, scale, conf}

    short8 (*XS)[16][64] = (short8(*)[16][64])BUF;          // [2][16][64]
    short8 (*PS)[64]     = (short8(*)[64])BUF;              // [16][64]
    short8 (*AS)[64]     = (short8(*)[64])(BUF + 16384);    // [16][64]

    const int tid    = threadIdx.x;
    const int lane   = tid & 63;
    const int w      = tid >> 6;          // 0..7
    const int mtl    = w >> 2;            // 0..1
    const int phw    = w & 3;             // this wave's ct within the block
    const int mtg    = blockIdx.x >> 2;   // 0..63
    const int ctbase = (blockIdx.x & 3) * 4;
    const int m0     = (mtg * 2 + mtl) * 16;
    const int row    = lane & 15;
    const int kg     = lane >> 4;

    // ---- 1) cooperative X staging: 32 rows, fp32 -> frag LDS + y2 ----
    {
        const int r = tid >> 4;           // 0..31
        const int j = tid & 15;
        const float* xrow = x + ((mtg * 2) * 16 + r) * DDIM;
        float ss = 0.0f;
        #pragma unroll
        for (int q = 0; q < 8; ++q) {
            float4 v = *(const float4*)(xrow + j * 4 + q * 64);
            ss += v.x*v.x + v.y*v.y + v.z*v.z + v.w*v.w;
            const int sfr = 2 * q + (j >> 3);
            const int kfr = (j >> 1) & 3;
            short4v h;
            h[0] = f2bfs(v.x); h[1] = f2bfs(v.y);
            h[2] = f2bfs(v.z); h[3] = f2bfs(v.w);
            *(short4v*)((unsigned short*)&XS[r >> 4][sfr][kfr * 16 + (r & 15)]
                        + (j & 1) * 4) = h;
        }
        #pragma unroll
        for (int off = 1; off < 16; off <<= 1)
            ss += __shfl_xor(ss, off, 64);
        if (j == 0) Y2S[r] = ss;
    }
    __syncthreads();

    // ---- 2) X fragments to registers; region becomes free ----
    short8 xv[16];
    #pragma unroll
    for (int s = 0; s < 16; ++s) xv[s] = XS[mtl][s][lane];
    __syncthreads();

    // ---- 3) P/A phases: stage raw fp32 -> bf16 frags + per-row scalars ----
    short8 pv[16], av[16];
    {
        const int r = tid >> 5;           // 0..15  (k-row local)
        const int j = tid & 31;
        #pragma unroll 1
        for (int ph = 0; ph < 4; ++ph) {
            const int kr = (ctbase + ph) * 16 + r;
            const float* prow = p_vals + kr * DDIM;
            const float* arow = a_vals + kr * DDIM;
            float pn2 = 0.f, an2 = 0.f, pa0 = 0.f;
            #pragma unroll
            for (int q = 0; q < 4; ++q) {
                float4 pv4 = *(const float4*)(prow + j * 4 + q * 128);
                float4 av4 = *(const float4*)(arow + j * 4 + q * 128);
                pn2 += pv4.x*pv4.x + pv4.y*pv4.y + pv4.z*pv4.z + pv4.w*pv4.w;
                an2 += av4.x*av4.x + av4.y*av4.y + av4.z*av4.z + av4.w*av4.w;
                pa0 += pv4.x*av4.x + pv4.y*av4.y + pv4.z*av4.z + pv4.w*av4.w;
                // col c = j*4 + q*128 -> s = (j>>3) + q*4, kg = (j>>1)&3
                const int sfr = (j >> 3) + q * 4;
                const int kfr = (j >> 1) & 3;
                short4v hp, ha;
                hp[0] = f2bfs(pv4.x); hp[1] = f2bfs(pv4.y);
                hp[2] = f2bfs(pv4.z); hp[3] = f2bfs(pv4.w);
                ha[0] = f2bfs(av4.x); ha[1] = f2bfs(av4.y);
                ha[2] = f2bfs(av4.z); ha[3] = f2bfs(av4.w);
                *(short4v*)((unsigned short*)&PS[sfr][kfr * 16 + r] + (j & 1) * 4) = hp;
                *(short4v*)((unsigned short*)&AS[sfr][kfr * 16 + r] + (j & 1) * 4) = ha;
            }
            #pragma unroll
            for (int off = 1; off < 32; off <<= 1) {
                pn2 += __shfl_xor(pn2, off, 64);
                an2 += __shfl_xor(an2, off, 64);
                pa0 += __shfl_xor(pa0, off, 64);
            }
            if (j == 0) {
                // expmap0 with c = 1 (reference fp32 semantics)
                float u     = fmaxf(sqrtf(pn2), 1e-5f);
                float t     = tanhf(fminf(u, 15.0f));
                float scale = t / u;
                float p2    = scale * scale * pn2;
                float conf  = 1.0f - p2;
                float na    = fmaxf(conf * sqrtf(an2), 1e-7f);
                float pa    = scale * conf * pa0;
                float lam   = 2.0f / (1.0f - fminf(p2, 0.9999f));
                float kc    = lam * na;
                SCL[ph][r][0] = p2;  SCL[ph][r][1] = pa;
                SCL[ph][r][2] = na;  SCL[ph][r][3] = kc;
                SCL[ph][r][4] = scale; SCL[ph][r][5] = conf;
            }
            __syncthreads();
            if (phw == ph) {
                #pragma unroll
                for (int s = 0; s < 16; ++s) pv[s] = PS[s][lane];
                #pragma unroll
                for (int s = 0; s < 16; ++s) av[s] = AS[s][lane];
            }
            __syncthreads();
        }
    }

    // ---- 4) MFMA burst: 4 independent chains of depth 8 ----
    f32x4 aP[2] = {{0.f,0.f,0.f,0.f},{0.f,0.f,0.f,0.f}};
    f32x4 aA[2] = {{0.f,0.f,0.f,0.f},{0.f,0.f,0.f,0.f}};
    #pragma unroll
    for (int s = 0; s < 16; ++s) {
        aP[s & 1] = __builtin_amdgcn_mfma_f32_16x16x32_bf16(xv[s], pv[s], aP[s & 1], 0, 0, 0);
        aA[s & 1] = __builtin_amdgcn_mfma_f32_16x16x32_bf16(xv[s], av[s], aA[s & 1], 0, 0, 0);
    }
    f32x4 accP = aP[0] + aP[1];
    f32x4 accA = aA[0] + aA[1];

    // ---- fused epilogue (scale/conf applied here) ----
    const int c = (ctbase + phw) * 16 + row;
    const float p2    = SCL[phw][row][0];
    const float pa    = SCL[phw][row][1];
    const float na    = SCL[phw][row][2];
    const float kc    = SCL[phw][row][3];
    const float scale = SCL[phw][row][4];
    const float conf  = SCL[phw][row][5];
    #pragma unroll
    for (int j = 0; j < 4; ++j) {
        const int m     = m0 + kg * 4 + j;
        const float y2n = Y2S[mtl * 16 + kg * 4 + j];
        const float xpv = scale * accP[j];
        const float xav = conf  * accA[j];
        // mobius_addition_batch(-p, x): xy = -xp
        const float alpha = 1.0f - 2.0f * xpv + y2n;       // 1 + 2c*xy + c*y2
        const float beta  = 1.0f - p2;                     // 1 - c*||p||^2
        const float gam   = 1.0f - 2.0f * xpv + p2 * y2n;  // denom
        const float gi    = __builtin_amdgcn_rcpf(gam + 1e-5f);
        const float num   = 2.0f * (beta * xav - alpha * pa) * gi;
        const float mob2  = (alpha*alpha*p2 + beta*beta*y2n
                             - 2.0f*alpha*beta*xpv) * gi * gi;
        const float den   = na * (1.0f - mob2);
        const float z     = num * __builtin_amdgcn_rcpf(den);
        // arsinh(z) = log(max(z + sqrt(1+z^2), 1e-5))
        const float arg   = fmaxf(z + __builtin_amdgcn_sqrtf(1.0f + z * z), 1e-5f);
        out[m * KROWS + c] = kc * __logf(arg);
    }
}

extern "C" void kernel_launch(void* const* d_in, const int* in_sizes, int n_in,
                              void* d_out, int out_size, void* d_ws, size_t ws_size,
                              hipStream_t stream) {
    (void)in_sizes; (void)n_in; (void)out_size; (void)d_ws; (void)ws_size;
    const float* x      = (const float*)d_in[0];
    const float* a_vals = (const float*)d_in[1];
    const float* p_vals = (const float*)d_in[2];
    float* out = (float*)d_out;

    // single dispatch: 64 mt-groups x 4 ct-groups = 256 blocks x 512 threads
    hmlr_one<<<256, 512, 0, stream>>>(x, a_vals, p_vals, out);
}

// Round 11
// 15.373 us; speedup vs baseline: 1.1774x; 1.1774x over previous
//
#include <hip/hip_runtime.h>
#include <hip/hip_bf16.h>
#include <math.h>

// Problem constants (fixed by the reference setup_inputs)
#define NROWS 2048
#define KROWS 256
#define DDIM  512

typedef __attribute__((ext_vector_type(8))) short short8;
typedef __attribute__((ext_vector_type(4))) short short4v;
typedef __attribute__((ext_vector_type(4))) float f32x4;

// Workspace layout (bytes) — bf16 P/A stored in MFMA-fragment order:
//   chunk index ((tile*16 + s)*64 + kg*16 + r) holds
//   T[tile*16 + r][s*32 + kg*8 .. +8] as short8, so a wave load at
//   base + s*64chunks + lane is 1KB coalesced and fragment-ready.
//   PT [K/16][16][64] short8 : @0        (262144 B)
//   AT [K/16][16][64] short8 : @262144   (262144 B)
//   SC [K] float4            : @524288   (4096 B)   {p2, pa, na, kc}
#define AB_BYTE   262144
#define SC_FOFF   131072   // float offset

__device__ inline short f2bfs(float f) {
    // fp32 -> bf16 RNE (inputs are finite)
    unsigned u = __float_as_uint(f);
    u += 0x7fffu + ((u >> 16) & 1u);
    return (short)(u >> 16);
}

__device__ inline float wave_reduce_sum(float v) {
    #pragma unroll
    for (int off = 32; off > 0; off >>= 1)
        v += __shfl_xor(v, off, 64);
    return v;
}

// Prep: 256 blocks x 64 threads, ONE k per block (full-GPU, ~minimal tail).
// expmap0 + conformal prep -> bf16 P/A in fragment order + SC scalars.
__global__ __launch_bounds__(64) void hmlr_prep(
        const float* __restrict__ a_vals,
        const float* __restrict__ p_vals,
        float* __restrict__ ws) {
    const int lane = threadIdx.x;
    const int k    = blockIdx.x;  // 0..255

    const float4* pv4 = (const float4*)(p_vals) + k * (DDIM / 4) + lane * 2;
    const float4* av4 = (const float4*)(a_vals) + k * (DDIM / 4) + lane * 2;
    float4 p0 = pv4[0], p1 = pv4[1];
    float4 a0 = av4[0], a1 = av4[1];

    float pn2 = p0.x*p0.x + p0.y*p0.y + p0.z*p0.z + p0.w*p0.w
              + p1.x*p1.x + p1.y*p1.y + p1.z*p1.z + p1.w*p1.w;
    float an2 = a0.x*a0.x + a0.y*a0.y + a0.z*a0.z + a0.w*a0.w
              + a1.x*a1.x + a1.y*a1.y + a1.z*a1.z + a1.w*a1.w;
    float pa0 = p0.x*a0.x + p0.y*a0.y + p0.z*a0.z + p0.w*a0.w
              + p1.x*a1.x + p1.y*a1.y + p1.z*a1.z + p1.w*a1.w;

    pn2 = wave_reduce_sum(pn2);
    an2 = wave_reduce_sum(an2);
    pa0 = wave_reduce_sum(pa0);

    // expmap0 with c = 1: p = tanh(clamp(||u||,15)) * u / ||u||
    float u     = fmaxf(sqrtf(pn2), 1e-5f);
    float t     = tanhf(fminf(u, 15.0f));
    float scale = t / u;
    float p2    = scale * scale * pn2;       // ||p_poincare||^2
    float conf  = 1.0f - p2;                 // conformal factor (c=1)
    float na    = fmaxf(conf * sqrtf(an2), 1e-7f);  // max(||a_poincare||, 1e-7)
    float pa    = scale * conf * pa0;        // dot(p_poincare, a_poincare)
    float lam   = 2.0f / (1.0f - fminf(p2, 0.9999f)); // 1/c - 1e-4 = 0.9999
    float kc    = lam * na;                  // / sqrt(c) = 1

    float pf[8] = { scale*p0.x, scale*p0.y, scale*p0.z, scale*p0.w,
                    scale*p1.x, scale*p1.y, scale*p1.z, scale*p1.w };
    float af[8] = { conf*a0.x, conf*a0.y, conf*a0.z, conf*a0.w,
                    conf*a1.x, conf*a1.y, conf*a1.z, conf*a1.w };
    short8 pu, au;
    #pragma unroll
    for (int j = 0; j < 8; ++j) {
        pu[j] = f2bfs(pf[j]);
        au[j] = f2bfs(af[j]);
    }
    // fragment-order scatter: s = lane>>2, kg = lane&3, r = k&15
    short8* PT8 = (short8*)ws;
    short8* AT8 = (short8*)((char*)ws + AB_BYTE);
    const int ci = (((k >> 4) * 16 + (lane >> 2)) * 64) + (lane & 3) * 16 + (k & 15);
    PT8[ci] = pu;
    AT8[ci] = au;
    if (lane == 0)
        ((float4*)(ws + SC_FOFF))[k] = make_float4(p2, pa, na, kc);
}

// Main MFMA kernel: block = 1 mt x 4 ct (one wave each), 512 blocks.
// Grid mapping mt = bid>>2, ctg = bid&3: with XCD = bid%8 round-robin, each
// XCD sees exactly one ctg (128KB P/A fragments -> its L2 stays warm).
// X tile (16 x 512 fp32, 32KB) cooperatively staged -> bf16 fragment LDS +
// y2 via 16-lane shfl reduce. P/A fragment preloads issued before staging.
// Epilogue results transposed through a padded LDS tile so each lane does
// one coalesced float4 store.
// C/D: col = lane&15 (class), row = (lane>>4)*4 + reg (m)   [m89 verified]
__global__ __launch_bounds__(256, 2) void hmlr_main(
        const float* __restrict__ x,
        const float* __restrict__ ws,
        float* __restrict__ out) {
    __shared__ short8 XS[16][64];    // 16KB bf16 X tile, fragment order
    __shared__ float  Y2S[16];
    __shared__ float  OT[4][16][20]; // padded transpose tile (5KB)

    const int tid  = threadIdx.x;
    const int lane = tid & 63;
    const int w    = tid >> 6;
    const int mt   = blockIdx.x >> 2;           // 0..127
    const int ct   = (blockIdx.x & 3) * 4 + w;  // 0..15
    const int m0   = mt * 16;
    const int c0   = ct * 16;
    const int row  = lane & 15;
    const int kg   = lane >> 4;

    const short8* PT8 = (const short8*)ws;
    const short8* AT8 = (const short8*)((const char*)ws + AB_BYTE);
    const float*  SC  = ws + SC_FOFF;

    // ---- issue P/A fragment preloads (overlap with X staging) ----
    const short8* pt = PT8 + ct * 16 * 64 + lane;
    const short8* at = AT8 + ct * 16 * 64 + lane;
    short8 pv[16], av[16];
    #pragma unroll
    for (int s = 0; s < 16; ++s) pv[s] = pt[s * 64];
    #pragma unroll
    for (int s = 0; s < 16; ++s) av[s] = at[s * 64];

    // ---- cooperative X staging: fp32 -> bf16 fragment-order LDS + y2 ----
    {
        const int r = tid >> 4;
        const int j = tid & 15;
        const float* xrow = x + (m0 + r) * DDIM;
        float ss = 0.0f;
        #pragma unroll
        for (int q = 0; q < 8; ++q) {
            float4 v = *(const float4*)(xrow + j * 4 + q * 64);
            ss += v.x*v.x + v.y*v.y + v.z*v.z + v.w*v.w;
            // c = q*64 + j*4 -> s = 2q + (j>>3), kg = (j>>1)&3, e = (j&1)*4
            const int sfr = 2 * q + (j >> 3);
            const int kfr = (j >> 1) & 3;
            short4v h;
            h[0] = f2bfs(v.x); h[1] = f2bfs(v.y);
            h[2] = f2bfs(v.z); h[3] = f2bfs(v.w);
            *(short4v*)((unsigned short*)&XS[sfr][kfr * 16 + r] + (j & 1) * 4) = h;
        }
        // row-sum over the 16 lanes of this row
        #pragma unroll
        for (int off = 1; off < 16; off <<= 1)
            ss += __shfl_xor(ss, off, 64);
        if (j == 0) Y2S[r] = ss;
    }
    __syncthreads();

    // ---- X fragments from LDS (consecutive b128, conflict-free) ----
    short8 xv[16];
    #pragma unroll
    for (int s = 0; s < 16; ++s) xv[s] = XS[s][lane];

    // ---- MFMA burst: 4 independent chains of depth 8 ----
    f32x4 aP[2] = {{0.f,0.f,0.f,0.f},{0.f,0.f,0.f,0.f}};
    f32x4 aA[2] = {{0.f,0.f,0.f,0.f},{0.f,0.f,0.f,0.f}};
    #pragma unroll
    for (int s = 0; s < 16; ++s) {
        aP[s & 1] = __builtin_amdgcn_mfma_f32_16x16x32_bf16(xv[s], pv[s], aP[s & 1], 0, 0, 0);
        aA[s & 1] = __builtin_amdgcn_mfma_f32_16x16x32_bf16(xv[s], av[s], aA[s & 1], 0, 0, 0);
    }
    f32x4 accP = aP[0] + aP[1];
    f32x4 accA = aA[0] + aA[1];

    // ---- fused epilogue -> padded LDS transpose ----
    const int c = c0 + row;
    f32x4 sc = *(const f32x4*)(SC + 4 * c);
    const float p2 = sc[0], pa = sc[1], na = sc[2], kc = sc[3];
    #pragma unroll
    for (int j = 0; j < 4; ++j) {
        const int mloc  = kg * 4 + j;
        const float y2n = Y2S[mloc];
        const float xpv = accP[j];
        const float xav = accA[j];
        // mobius_addition_batch(-p, x): xy = -xp
        const float alpha = 1.0f - 2.0f * xpv + y2n;       // 1 + 2c*xy + c*y2
        const float beta  = 1.0f - p2;                     // 1 - c*||p||^2
        const float gam   = 1.0f - 2.0f * xpv + p2 * y2n;  // denom
        const float gi    = __builtin_amdgcn_rcpf(gam + 1e-5f);
        const float num   = 2.0f * (beta * xav - alpha * pa) * gi;
        const float mob2  = (alpha*alpha*p2 + beta*beta*y2n
                             - 2.0f*alpha*beta*xpv) * gi * gi;
        const float den   = na * (1.0f - mob2);
        const float z     = num * __builtin_amdgcn_rcpf(den);
        // arsinh(z) = log(max(z + sqrt(1+z^2), 1e-5))
        const float arg   = fmaxf(z + __builtin_amdgcn_sqrtf(1.0f + z * z), 1e-5f);
        OT[w][mloc][row]  = kc * __logf(arg);
    }
    __syncthreads();   // OT is wave-local but keep lifetimes clean across waves

    // ---- coalesced store: lane -> (m_local = lane>>2, quad = lane&3) ----
    {
        const int mloc = lane >> 2;
        const int q    = lane & 3;
        float4 o = make_float4(OT[w][mloc][q * 4 + 0], OT[w][mloc][q * 4 + 1],
                               OT[w][mloc][q * 4 + 2], OT[w][mloc][q * 4 + 3]);
        *(float4*)(out + (m0 + mloc) * KROWS + c0 + q * 4) = o;
    }
}

extern "C" void kernel_launch(void* const* d_in, const int* in_sizes, int n_in,
                              void* d_out, int out_size, void* d_ws, size_t ws_size,
                              hipStream_t stream) {
    (void)in_sizes; (void)n_in; (void)out_size; (void)ws_size;
    const float* x      = (const float*)d_in[0];
    const float* a_vals = (const float*)d_in[1];
    const float* p_vals = (const float*)d_in[2];
    float* ws  = (float*)d_ws;
    float* out = (float*)d_out;

    // prep: 256 blocks x 64 threads, one k per block (full GPU, short tail)
    hmlr_prep<<<256, 64, 0, stream>>>(a_vals, p_vals, ws);
    // main: 128 mt x 4 ct-groups = 512 blocks, self-contained X staging
    hmlr_main<<<512, 256, 0, stream>>>(x, ws, out);
}